// Round 13
// baseline (135.343 us; speedup 1.0000x reference)
//
#include <hip/hip_runtime.h>
#include <hip/hip_fp16.h>

typedef _Float16 f16x8 __attribute__((ext_vector_type(8)));
typedef float f32x4 __attribute__((ext_vector_type(4)));
typedef unsigned int uint32;

#define LDW 136   // row stride in halves (272B: 16B-aligned)

// wait only lgkmcnt(0): vmcnt=63, expcnt=7, lgkmcnt=0 -> 0xC07F
// sched_barrier(0) after: rule #18 (compiler may hoist MFMA past the wait)
#define WAITLGKM() do { __builtin_amdgcn_s_waitcnt(0xC07F); __builtin_amdgcn_sched_barrier(0); } while(0)

union F16x8U { f16x8 v; __half2 h2[4]; uint2 u2[2]; uint4 u4; };

__device__ __forceinline__ uint32 pk2f(float a, float b) {
  __half2 h = __floats2half2_rn(a, b);
  return *reinterpret_cast<uint32*>(&h);
}
__device__ __forceinline__ float bcast(float v, int sl) {
  return __int_as_float(__builtin_amdgcn_readlane(__float_as_int(v), sl));
}
template <int CTRL, int RMASK = 0xF, int BMASK = 0xF>
__device__ __forceinline__ float dppmov(float v) {
  return __int_as_float(__builtin_amdgcn_update_dpp(
      0, __float_as_int(v), CTRL, RMASK, BMASK, true));
}
template <int PAT>
__device__ __forceinline__ float swzf(float v) {
  return __int_as_float(__builtin_amdgcn_ds_swizzle(__float_as_int(v), PAT));
}
__device__ __forceinline__ f16x8 ldsv8(const __half* p) {
  return *reinterpret_cast<const f16x8*>(p);   // ds_read_b128
}
__device__ __forceinline__ f32x4 mfma16(f16x8 a, f16x8 b, f32x4 c) {
  return __builtin_amdgcn_mfma_f32_16x16x32_f16(a, b, c, 0, 0, 0);
}
// packed C-frag store: C[m][n=fr] -> row-major act[tok=fr][c], 1x ds_write_b64
__device__ __forceinline__ void stp8(__half* base, int fr, int fq, int nt, f32x4 a) {
  uint2 u; u.x = pk2f(a[0], a[1]); u.y = pk2f(a[2], a[3]);
  *reinterpret_cast<uint2*>(&base[fr * LDW + nt * 16 + fq * 4]) = u;
}

// ---- workspace layout (halves) ----
#define OFF_WQ   0          // wqT  [c_out 128][c_in 128]
#define OFF_WK2  16384      // wk2  [h 4][i 128][d 40] : wkv[i][h*32+d] (d<32, pad 0)
#define OFF_WV   36864      // wvT  [c_out 128][i 128] : wkv[i][128+c]
#define OFF_WMH  53248      // wmhT
#define OFF_W1   69632      // w1T
#define OFF_W2   86016      // w2T
#define WS_HALVES 102400

__global__ void prep_weights(const float* __restrict__ wq, const float* __restrict__ wkv,
                             const float* __restrict__ wmh, const float* __restrict__ w1,
                             const float* __restrict__ w2, __half* __restrict__ ws) {
  int idx = blockIdx.x * 256 + threadIdx.x;
  if (idx >= WS_HALVES) return;
  float v;
  if (idx < OFF_WK2) {
    int t = idx, c = t >> 7, k = t & 127;
    v = wq[k * 128 + c];
  } else if (idx < OFF_WV) {
    int t = idx - OFF_WK2;
    int d = t % 40, row = t / 40;            // row = h*128 + i
    int h = row >> 7, i = row & 127;
    v = (d < 32) ? wkv[i * 256 + h * 32 + d] : 0.f;
  } else if (idx < OFF_WMH) {
    int t = idx - OFF_WV, c = t >> 7, k = t & 127;
    v = wkv[k * 256 + 128 + c];
  } else if (idx < OFF_W1) {
    int t = idx - OFF_WMH, c = t >> 7, k = t & 127;
    v = wmh[k * 128 + c];
  } else if (idx < OFF_W2) {
    int t = idx - OFF_W1, c = t >> 7, k = t & 127;
    v = w1[k * 128 + c];
  } else {
    int t = idx - OFF_W2, c = t >> 7, k = t & 127;
    v = w2[k * 128 + c];
  }
  ws[idx] = __float2half_rn(v);
}

// One wave = 8 tokens end-to-end. No s_barrier anywhere: all LDS is
// wave-private, every producer->consumer handoff is a wave-local lgkmcnt(0).
__global__ void __launch_bounds__(64, 3) ca_wave(
    const float* __restrict__ xq, const float* __restrict__ kvin,
    const __half* __restrict__ wsv,
    const float* __restrict__ bmh, const float* __restrict__ b1,
    const float* __restrict__ b2,
    const float* __restrict__ g1, const float* __restrict__ bb1,
    const float* __restrict__ g2, const float* __restrict__ bb2,
    float* __restrict__ outp)
{
  // 48 rows x LDW x 2B = 13056 B -> 12 blocks(waves)/CU, all independent
  __shared__ __half WS[48 * LDW];

  const int lane = threadIdx.x;
  const int fr = lane & 15, fq = lane >> 4;   // MFMA frag row / k-group
  const int fr8 = fr & 7;
  const bool act = fr < 8;                    // token lanes (8 tokens/wave)
  const int wtok = blockIdx.x * 8;            // this wave's first token

  __half* qwp = WS;                 // rows 0-31: qw/ctx [h*8 + tok]
  __half* arA = WS + 32 * LDW;      // rows 32-39: Xh -> kv0 -> out -> h
  __half* arB = WS + 40 * LDW;      // rows 40-47: Q  -> kv1 -> res

  const f32x4 ZZ = {0.f, 0.f, 0.f, 0.f};
  const float SCALE = 0.17677669529663687f;   // 1/sqrt(32)

  // ---- prefetch kv for token pair 0 ----
  float4 pre[2][4];
#pragma unroll
  for (int st = 0; st < 2; ++st) {
    const float4* kv4 = reinterpret_cast<const float4*>(kvin + (size_t)(wtok + st) * 1024);
    pre[st][0] = kv4[2 * lane];       pre[st][1] = kv4[2 * lane + 1];
    pre[st][2] = kv4[2 * lane + 128]; pre[st][3] = kv4[2 * lane + 129];
  }

  // ---- Xh: 8 tokens f16 -> arA rows 0-7 ----
#pragma unroll
  for (int c = 0; c < 2; ++c) {
    int idx = lane + c * 64;
    int tok = idx >> 4, ko = (idx & 15) * 8;
    const float4* s0 = reinterpret_cast<const float4*>(xq + (size_t)(wtok + tok) * 128 + ko);
    float4 a = s0[0], b = s0[1];
    uint4 u; u.x = pk2f(a.x, a.y); u.y = pk2f(a.z, a.w);
    u.z = pk2f(b.x, b.y); u.w = pk2f(b.z, b.w);
    *reinterpret_cast<uint4*>(&arA[tok * LDW + ko]) = u;
  }
  WAITLGKM();

  // ---- P1: Q = Wq(A) @ X(B) -> arB rows 0-7 (B-cols tok=fr, fr>=8 discarded) ----
  {
    f16x8 bx[4];
#pragma unroll
    for (int ks = 0; ks < 4; ++ks) bx[ks] = ldsv8(&arA[fr8 * LDW + ks * 32 + fq * 8]);
#pragma unroll
    for (int nt = 0; nt < 8; ++nt) {
      f32x4 acc = ZZ;
#pragma unroll
      for (int ks = 0; ks < 4; ++ks) {
        f16x8 a_ = *reinterpret_cast<const f16x8*>(
            wsv + OFF_WQ + (nt * 16 + fr) * 128 + ks * 32 + fq * 8);
        acc = mfma16(a_, bx[ks], acc);
      }
      if (act) stp8(arB, fr, fq, nt, acc);
    }
  }
  WAITLGKM();

  // ---- P2: qw[h][tok][i] = wk2[h](A) @ q(B) -> qwp rows h*8+tok ----
#pragma unroll
  for (int h = 0; h < 4; ++h) {
    f16x8 aq = ldsv8(&arB[fr8 * LDW + h * 32 + fq * 8]);
#pragma unroll
    for (int nt = 0; nt < 8; ++nt) {
      f16x8 a_ = *reinterpret_cast<const f16x8*>(
          wsv + OFF_WK2 + (size_t)((h * 128 + nt * 16 + fr) * 40 + fq * 8));
      f32x4 acc = mfma16(a_, aq, ZZ);
      if (act) {
        uint2 u; u.x = pk2f(acc[0], acc[1]); u.y = pk2f(acc[2], acc[3]);
        *reinterpret_cast<uint2*>(&qwp[(h * 8 + fr) * LDW + nt * 16 + fq * 4]) = u;
      }
    }
  }

  // ---- P3: attention, 4 token-pairs (dual independent chains per iter) ----
  {
    const int kr = lane >> 4, i8v = (lane & 15) * 8, l2 = 2 * lane;
    __half* const kvs[2] = {arA, arB};   // Xh/Q dead after P1/P2
#pragma unroll 1
    for (int t2 = 0; t2 < 4; ++t2) {
      WAITLGKM();   // prior reads of arA/arB complete (WAR)
#pragma unroll
      for (int st = 0; st < 2; ++st) {
        uint4 u0, u1;
        u0.x = pk2f(pre[st][0].x, pre[st][0].y); u0.y = pk2f(pre[st][0].z, pre[st][0].w);
        u0.z = pk2f(pre[st][1].x, pre[st][1].y); u0.w = pk2f(pre[st][1].z, pre[st][1].w);
        u1.x = pk2f(pre[st][2].x, pre[st][2].y); u1.y = pk2f(pre[st][2].z, pre[st][2].w);
        u1.z = pk2f(pre[st][3].x, pre[st][3].y); u1.w = pk2f(pre[st][3].z, pre[st][3].w);
        *reinterpret_cast<uint4*>(&kvs[st][kr * LDW + i8v]) = u0;        // rows 0..3
        *reinterpret_cast<uint4*>(&kvs[st][(4 + kr) * LDW + i8v]) = u1;  // rows 4..7
      }
      if (t2 < 3) {   // prefetch next pair
#pragma unroll
        for (int st = 0; st < 2; ++st) {
          const float4* kv4 = reinterpret_cast<const float4*>(
              kvin + (size_t)(wtok + 2 * t2 + 2 + st) * 1024);
          pre[st][0] = kv4[2 * lane];       pre[st][1] = kv4[2 * lane + 1];
          pre[st][2] = kv4[2 * lane + 128]; pre[st][3] = kv4[2 * lane + 129];
        }
      }
      WAITLGKM();   // kv visible within wave
      // sim via MFMA: A = qw rows (h=fr&3, tok), B = kv rows (k=fr&7)
      f32x4 sim[2];
#pragma unroll
      for (int st = 0; st < 2; ++st) {
        f32x4 a = ZZ;
#pragma unroll
        for (int ks = 0; ks < 4; ++ks) {
          f16x8 a_ = ldsv8(&qwp[((fr & 3) * 8 + 2 * t2 + st) * LDW + ks * 32 + fq * 8]);
          f16x8 b_ = ldsv8(&kvs[st][fr8 * LDW + ks * 32 + fq * 8]);
          a = mfma16(a_, b_, a);
        }
        sim[st] = a;
      }
      // softmax over k (8 lanes): quad_perm DPP xor1/xor2 + swizzle xor4
      float at_[2][4];
#pragma unroll
      for (int st = 0; st < 2; ++st) {
#pragma unroll
        for (int r = 0; r < 4; ++r) {
          float s = sim[st][r] * SCALE;
          float mx = fmaxf(s, dppmov<0xB1>(s));
          mx = fmaxf(mx, dppmov<0x4E>(mx));
          mx = fmaxf(mx, swzf<0x101F>(mx));
          float e = __expf(s - mx);
          float dn = e + dppmov<0xB1>(e);
          dn += dppmov<0x4E>(dn);
          dn += swzf<0x101F>(dn);
          at_[st][r] = __fdividef(e, dn);   // lane k holds attn[h=r][k]
        }
      }
      // ctx[h][c] = sum_k at*kv ; lane owns cols 2*lane, 2*lane+1
#pragma unroll
      for (int st = 0; st < 2; ++st) {
        __half2 kvc[8];
#pragma unroll
        for (int k = 0; k < 8; ++k)
          kvc[k] = *reinterpret_cast<const __half2*>(&kvs[st][k * LDW + l2]);
#pragma unroll
        for (int h = 0; h < 4; ++h) {
          float c0 = 0.f, c1 = 0.f;
#pragma unroll
          for (int k = 0; k < 8; ++k) {
            float a = bcast(at_[st][h], k);
            float2 kf = __half22float2(kvc[k]);
            c0 = fmaf(a, kf.x, c0);
            c1 = fmaf(a, kf.y, c1);
          }
          *reinterpret_cast<__half2*>(&qwp[(h * 8 + 2 * t2 + st) * LDW + l2]) =
              __floats2half2_rn(c0, c1);
        }
      }
    }
  }
  WAITLGKM();

  // ---- P4: out[tok][c] = WvT(A) @ ctx[h(c)](B) -> arA rows 0-7 ----
#pragma unroll
  for (int h = 0; h < 4; ++h) {
    f16x8 bc[4];
#pragma unroll
    for (int ks = 0; ks < 4; ++ks)
      bc[ks] = ldsv8(&qwp[(h * 8 + fr8) * LDW + ks * 32 + fq * 8]);
#pragma unroll
    for (int j = 0; j < 2; ++j) {
      int nt = 2 * h + j;
      f32x4 acc = ZZ;
#pragma unroll
      for (int ks = 0; ks < 4; ++ks) {
        f16x8 a_ = *reinterpret_cast<const f16x8*>(
            wsv + OFF_WV + (nt * 16 + fr) * 128 + ks * 32 + fq * 8);
        acc = mfma16(a_, bc[ks], acc);
      }
      if (act) stp8(arA, fr, fq, nt, acc);
    }
  }
  // residual x in C-frag layout (token fr8, cols nt*16+fq*4)
  float4 xr[8];
#pragma unroll
  for (int nt = 0; nt < 8; ++nt)
    xr[nt] = *reinterpret_cast<const float4*>(
        xq + (size_t)(wtok + fr8) * 128 + nt * 16 + fq * 4);
  WAITLGKM();

  // ---- P5: y = Wmh(A) @ out(B), full row in regs (vv[32] covers c for token fr) ----
  float vv[32];
  {
    f16x8 bo[4];
#pragma unroll
    for (int ks = 0; ks < 4; ++ks) bo[ks] = ldsv8(&arA[fr8 * LDW + ks * 32 + fq * 8]);
#pragma unroll
    for (int nt = 0; nt < 8; ++nt) {
      f32x4 acc = ZZ;
#pragma unroll
      for (int ks = 0; ks < 4; ++ks) {
        f16x8 a_ = *reinterpret_cast<const f16x8*>(
            wsv + OFF_WMH + (nt * 16 + fr) * 128 + ks * 32 + fq * 8);
        acc = mfma16(a_, bo[ks], acc);
      }
      float4 bm = *reinterpret_cast<const float4*>(&bmh[nt * 16 + fq * 4]);
      vv[nt * 4 + 0] = acc[0] + bm.x; vv[nt * 4 + 1] = acc[1] + bm.y;
      vv[nt * 4 + 2] = acc[2] + bm.z; vv[nt * 4 + 3] = acc[3] + bm.w;
    }
  }
  // ---- LN1 wave-local: combine 4 fq-lanes of token fr (xor16 swz + xor32 shfl) ----
  {
    float s = 0.f, sq = 0.f;
#pragma unroll
    for (int r = 0; r < 32; ++r) { s += vv[r]; sq = fmaf(vv[r], vv[r], sq); }
    s += swzf<0x401F>(s);  s += __shfl_xor(s, 32);
    sq += swzf<0x401F>(sq); sq += __shfl_xor(sq, 32);
    float mu = s * 0.0078125f;
    float var = sq * 0.0078125f - mu * mu;
    float rstd = rsqrtf(var + 1e-5f);
#pragma unroll
    for (int nt = 0; nt < 8; ++nt) {
      float4 g = *reinterpret_cast<const float4*>(&g1[nt * 16 + fq * 4]);
      float4 c = *reinterpret_cast<const float4*>(&bb1[nt * 16 + fq * 4]);
      float r0 = (vv[nt * 4 + 0] - mu) * rstd * g.x + c.x + xr[nt].x;
      float r1 = (vv[nt * 4 + 1] - mu) * rstd * g.y + c.y + xr[nt].y;
      float r2 = (vv[nt * 4 + 2] - mu) * rstd * g.z + c.z + xr[nt].z;
      float r3 = (vv[nt * 4 + 3] - mu) * rstd * g.w + c.w + xr[nt].w;
      uint2 u; u.x = pk2f(r0, r1); u.y = pk2f(r2, r3);
      if (act) *reinterpret_cast<uint2*>(&arB[fr * LDW + nt * 16 + fq * 4]) = u;  // res
    }
  }
  WAITLGKM();

  // ---- P6: h = gelu(W1(A) @ res(B) + b1) -> arA rows 0-7 ----
  {
    f16x8 br[4];
#pragma unroll
    for (int ks = 0; ks < 4; ++ks) br[ks] = ldsv8(&arB[fr8 * LDW + ks * 32 + fq * 8]);
#pragma unroll
    for (int nt = 0; nt < 8; ++nt) {
      f32x4 acc = ZZ;
#pragma unroll
      for (int ks = 0; ks < 4; ++ks) {
        f16x8 a_ = *reinterpret_cast<const f16x8*>(
            wsv + OFF_W1 + (nt * 16 + fr) * 128 + ks * 32 + fq * 8);
        acc = mfma16(a_, br[ks], acc);
      }
      float4 bb = *reinterpret_cast<const float4*>(&b1[nt * 16 + fq * 4]);
      float t0, t1;
      uint2 u;
      t0 = acc[0] + bb.x; t0 = 0.5f * t0 * (1.f + erff(t0 * 0.70710678118654752f));
      t1 = acc[1] + bb.y; t1 = 0.5f * t1 * (1.f + erff(t1 * 0.70710678118654752f));
      u.x = pk2f(t0, t1);
      t0 = acc[2] + bb.z; t0 = 0.5f * t0 * (1.f + erff(t0 * 0.70710678118654752f));
      t1 = acc[3] + bb.w; t1 = 0.5f * t1 * (1.f + erff(t1 * 0.70710678118654752f));
      u.y = pk2f(t0, t1);
      if (act) *reinterpret_cast<uint2*>(&arA[fr * LDW + nt * 16 + fq * 4]) = u;
    }
  }
  WAITLGKM();

  // ---- P7: v = W2(A) @ h(B) + b2 + res ; LN2 ; coalesced store from C-frag ----
  float ww[32];
  {
    f16x8 bh[4];
#pragma unroll
    for (int ks = 0; ks < 4; ++ks) bh[ks] = ldsv8(&arA[fr8 * LDW + ks * 32 + fq * 8]);
#pragma unroll
    for (int nt = 0; nt < 8; ++nt) {
      f32x4 acc = ZZ;
#pragma unroll
      for (int ks = 0; ks < 4; ++ks) {
        f16x8 a_ = *reinterpret_cast<const f16x8*>(
            wsv + OFF_W2 + (nt * 16 + fr) * 128 + ks * 32 + fq * 8);
        acc = mfma16(a_, bh[ks], acc);
      }
      float4 bb = *reinterpret_cast<const float4*>(&b2[nt * 16 + fq * 4]);
      F16x8U rr;
      rr.u2[0] = *reinterpret_cast<const uint2*>(&arB[fr8 * LDW + nt * 16 + fq * 4]);
      float2 p0 = __half22float2(rr.h2[0]), p1 = __half22float2(rr.h2[1]);
      ww[nt * 4 + 0] = acc[0] + bb.x + p0.x;
      ww[nt * 4 + 1] = acc[1] + bb.y + p0.y;
      ww[nt * 4 + 2] = acc[2] + bb.z + p1.x;
      ww[nt * 4 + 3] = acc[3] + bb.w + p1.y;
    }
  }
  {
    float s = 0.f, sq = 0.f;
#pragma unroll
    for (int r = 0; r < 32; ++r) { s += ww[r]; sq = fmaf(ww[r], ww[r], sq); }
    s += swzf<0x401F>(s);  s += __shfl_xor(s, 32);
    sq += swzf<0x401F>(sq); sq += __shfl_xor(sq, 32);
    float mu = s * 0.0078125f;
    float var = sq * 0.0078125f - mu * mu;
    float rstd = rsqrtf(var + 1e-5f);
    float* orow = outp + (size_t)(wtok + fr8) * 128;
#pragma unroll
    for (int nt = 0; nt < 8; ++nt) {
      float4 g = *reinterpret_cast<const float4*>(&g2[nt * 16 + fq * 4]);
      float4 c = *reinterpret_cast<const float4*>(&bb2[nt * 16 + fq * 4]);
      float4 o;
      o.x = (ww[nt * 4 + 0] - mu) * rstd * g.x + c.x;
      o.y = (ww[nt * 4 + 1] - mu) * rstd * g.y + c.y;
      o.z = (ww[nt * 4 + 2] - mu) * rstd * g.z + c.z;
      o.w = (ww[nt * 4 + 3] - mu) * rstd * g.w + c.w;
      if (act) *reinterpret_cast<float4*>(orow + nt * 16 + fq * 4) = o;
    }
  }
}

extern "C" void kernel_launch(void* const* d_in, const int* in_sizes, int n_in,
                              void* d_out, int out_size, void* d_ws, size_t ws_size,
                              hipStream_t stream) {
  const float* xq = (const float*)d_in[0];
  const float* kv = (const float*)d_in[1];
  const float* wkv = (const float*)d_in[2];
  const float* wq = (const float*)d_in[3];
  const float* wmh = (const float*)d_in[4];
  const float* bmh = (const float*)d_in[5];
  const float* b1 = (const float*)d_in[7];
  const float* w1 = (const float*)d_in[6];
  const float* w2 = (const float*)d_in[8];
  const float* b2 = (const float*)d_in[9];
  const float* g1 = (const float*)d_in[10];
  const float* bb1 = (const float*)d_in[11];
  const float* g2 = (const float*)d_in[12];
  const float* bb2 = (const float*)d_in[13];
  __half* ws = (__half*)d_ws;

  prep_weights<<<(WS_HALVES + 255) / 256, 256, 0, stream>>>(wq, wkv, wmh, w1, w2, ws);

  const int tokens = 32768;
  ca_wave<<<tokens / 8, 64, 0, stream>>>(xq, kv, ws, bmh, b1, b2,
                                         g1, bb1, g2, bb2, (float*)d_out);
}

// Round 14
// 56.876 us; speedup vs baseline: 2.3796x; 2.3796x over previous
//
#include <hip/hip_runtime.h>
#include <hip/hip_fp16.h>

typedef _Float16 f16x8 __attribute__((ext_vector_type(8)));
typedef float f32x4 __attribute__((ext_vector_type(4)));
typedef unsigned int uint32;

#define LDW 136   // row stride in halves (272B: 16B-aligned)
#define TB  32    // tokens per block: two independent 16-token streams

// wait only lgkmcnt(0): vmcnt=63, expcnt=7, lgkmcnt=0 -> 0xC07F
#define WAITLGKM() do { __builtin_amdgcn_s_waitcnt(0xC07F); __builtin_amdgcn_sched_barrier(0); } while(0)

// lgkm-only barrier: leaves global (VGPR-destined) prefetches in flight.
#define BAR() do {                                          \
  asm volatile("s_waitcnt lgkmcnt(0)" ::: "memory");        \
  __builtin_amdgcn_sched_barrier(0);                        \
  __builtin_amdgcn_s_barrier();                             \
  __builtin_amdgcn_sched_barrier(0);                        \
} while (0)

union F16x8U { f16x8 v; __half2 h2[4]; uint2 u2[2]; uint4 u4; };

__device__ __forceinline__ uint32 pk2f(float a, float b) {
  __half2 h = __floats2half2_rn(a, b);
  return *reinterpret_cast<uint32*>(&h);
}
__device__ __forceinline__ float bcast(float v, int sl) {
  return __int_as_float(__builtin_amdgcn_readlane(__float_as_int(v), sl));
}
template <int CTRL, int RMASK = 0xF, int BMASK = 0xF>
__device__ __forceinline__ float dppmov(float v) {
  return __int_as_float(__builtin_amdgcn_update_dpp(
      0, __float_as_int(v), CTRL, RMASK, BMASK, true));
}
template <int PAT>
__device__ __forceinline__ float swzf(float v) {
  return __int_as_float(__builtin_amdgcn_ds_swizzle(__float_as_int(v), PAT));
}
__device__ __forceinline__ f16x8 ldsv8(const __half* p) {
  return *reinterpret_cast<const f16x8*>(p);   // ds_read_b128
}
__device__ __forceinline__ f32x4 mfma16(f16x8 a, f16x8 b, f32x4 c) {
  return __builtin_amdgcn_mfma_f32_16x16x32_f16(a, b, c, 0, 0, 0);
}
// packed C-frag store: C[m][n=fr] -> row-major act[tok=fr][c], 1x ds_write_b64
__device__ __forceinline__ void stp(__half* base, int fr, int fq, int nt, f32x4 a) {
  uint2 u; u.x = pk2f(a[0], a[1]); u.y = pk2f(a[2], a[3]);
  *reinterpret_cast<uint2*>(&base[fr * LDW + nt * 16 + fq * 4]) = u;
}

// ---- workspace layout (halves) ----
#define OFF_WQ   0          // wqT  [c_out 128][c_in 128]
#define OFF_WK2  16384      // wk2  [h 4][i 128][d 40] : wkv[i][h*32+d] (d<32, pad 0)
#define OFF_WV   36864      // wvT  [c_out 128][i 128] : wkv[i][128+c]
#define OFF_WMH  53248      // wmhT
#define OFF_W1   69632      // w1T
#define OFF_W2   86016      // w2T
#define WS_HALVES 102400

__global__ void prep_weights(const float* __restrict__ wq, const float* __restrict__ wkv,
                             const float* __restrict__ wmh, const float* __restrict__ w1,
                             const float* __restrict__ w2, __half* __restrict__ ws) {
  int idx = blockIdx.x * 256 + threadIdx.x;
  if (idx >= WS_HALVES) return;
  float v;
  if (idx < OFF_WK2) {
    int t = idx, c = t >> 7, k = t & 127;
    v = wq[k * 128 + c];
  } else if (idx < OFF_WV) {
    int t = idx - OFF_WK2;
    int d = t % 40, row = t / 40;            // row = h*128 + i
    int h = row >> 7, i = row & 127;
    v = (d < 32) ? wkv[i * 256 + h * 32 + d] : 0.f;
  } else if (idx < OFF_WMH) {
    int t = idx - OFF_WV, c = t >> 7, k = t & 127;
    v = wkv[k * 256 + 128 + c];
  } else if (idx < OFF_W1) {
    int t = idx - OFF_WMH, c = t >> 7, k = t & 127;
    v = wmh[k * 128 + c];
  } else if (idx < OFF_W2) {
    int t = idx - OFF_W1, c = t >> 7, k = t & 127;
    v = w1[k * 128 + c];
  } else {
    int t = idx - OFF_W2, c = t >> 7, k = t & 127;
    v = w2[k * 128 + c];
  }
  ws[idx] = __float2half_rn(v);
}

// load W frags (2 c_out-tiles x 4 k-slices), used as MFMA *A* operand (shared by streams)
#define LOADB2(GOFF, NT0, NT1, BF) do {                                          \
  _Pragma("unroll")                                                              \
  for (int t_ = 0; t_ < 2; ++t_) {                                               \
    int nt_ = t_ ? (NT1) : (NT0);                                                \
    _Pragma("unroll")                                                            \
    for (int ks_ = 0; ks_ < 4; ++ks_)                                            \
      BF[t_][ks_] = *reinterpret_cast<const f16x8*>(                             \
          wsv + (GOFF) + (nt_*16 + fr)*128 + ks_*32 + fq*8);                     \
  } } while (0)

// two 16x16 tiles: A = weights (BF), B = activation tile (row-major [tok][c])
#define GEMM2(AT, BF, ACC0, ACC1) do {                                           \
  _Pragma("unroll")                                                              \
  for (int ks_ = 0; ks_ < 4; ++ks_) {                                            \
    f16x8 b_ = ldsv8(&(AT)[fr * LDW + ks_ * 32 + fq * 8]);                       \
    ACC0 = mfma16(BF[0][ks_], b_, ACC0);                                         \
    ACC1 = mfma16(BF[1][ks_], b_, ACC1);                                         \
  } } while (0)

__global__ void __launch_bounds__(256, 3) ca_mfma(
    const float* __restrict__ xq, const float* __restrict__ kvin,
    const __half* __restrict__ wsv,
    const float* __restrict__ bmh, const float* __restrict__ b1,
    const float* __restrict__ b2,
    const float* __restrict__ g1, const float* __restrict__ bb1,
    const float* __restrict__ g2, const float* __restrict__ bb2,
    float* __restrict__ outp)
{
  // LDS: 34816 + 17408 + 1024 = 53248 B -> 3 blocks/CU
  __shared__ __half QWC[2 * 64 * LDW];   // per stream: qw/ctx rows 0-63; RESb 16-31, Hb 32-47 reuse
  __shared__ __half UBUF[2 * 32 * LDW];  // per stream: kvw arena -> Ob(0-15)
  __shared__ float  PART[2][2][16][4];   // [stream][s|sq][tok][wave] LN partials

  const int tid = threadIdx.x;
  const int wv = tid >> 6, lane = tid & 63;
  const int fr = lane & 15, fq = lane >> 4;   // MFMA frag row / k-group
  const int tb = blockIdx.x * TB;
  const int ltb = wv * 4;
  const int cA = wv * 16 + fq * 4, cB = 64 + cA;   // this lane's C-frag columns

  __half* const QWs[2] = {QWC, QWC + 64 * LDW};
  __half* const Us[2]  = {UBUF, UBUF + 32 * LDW};

  const f32x4 ZZ = {0.f, 0.f, 0.f, 0.f};

  // ---- entry: issue ALL P1/P2 inputs + kv prefetch (no staging, no barrier) ----
  // x as direct B-frag: lane(fr,fq) holds x[tok=fr][ks*32+fq*8 .. +8]
  f16x8 bx[2][4];
#pragma unroll
  for (int st = 0; st < 2; ++st) {
    const float* xrow = xq + (size_t)(tb + st * 16 + fr) * 128 + fq * 8;
#pragma unroll
    for (int ks = 0; ks < 4; ++ks) {
      float4 a = *reinterpret_cast<const float4*>(xrow + ks * 32);
      float4 b = *reinterpret_cast<const float4*>(xrow + ks * 32 + 4);
      F16x8U u;
      u.u2[0].x = pk2f(a.x, a.y); u.u2[0].y = pk2f(a.z, a.w);
      u.u2[1].x = pk2f(b.x, b.y); u.u2[1].y = pk2f(b.z, b.w);
      bx[st][ks] = u.v;
    }
  }
  f16x8 bf[2][4];
  LOADB2(OFF_WQ, 2 * wv, 2 * wv + 1, bf);   // wave computes the Q-cols its own P2 needs
  f16x8 bq[8];                               // P2's A = wk2 rows (head wv), K=32
#pragma unroll
  for (int nt = 0; nt < 8; ++nt)
    bq[nt] = *reinterpret_cast<const f16x8*>(
        wsv + OFF_WK2 + (wv * 128 + nt * 16 + fr) * 40 + fq * 8);
  float4 pre[2][4];
#pragma unroll
  for (int st = 0; st < 2; ++st) {
    const float4* kv4 = reinterpret_cast<const float4*>(
        kvin + (size_t)(tb + st * 16 + ltb) * 1024);
    pre[st][0] = kv4[2 * lane];       pre[st][1] = kv4[2 * lane + 1];
    pre[st][2] = kv4[2 * lane + 128]; pre[st][3] = kv4[2 * lane + 129];
  }

  // ---- P1 + register handoff + P2 (all wave-local, no LDS roundtrip, no barrier) ----
#pragma unroll
  for (int st = 0; st < 2; ++st) {
    f32x4 aA = ZZ, aB = ZZ;
#pragma unroll
    for (int ks = 0; ks < 4; ++ks) {
      aA = mfma16(bf[0][ks], bx[st][ks], aA);   // q cols 32wv..+16
      aB = mfma16(bf[1][ks], bx[st][ks], aB);   // q cols 32wv+16..+32
    }
    // C-frag(f32) -> P2 B-frag(f16): verified mapping (R6).
    // target lane (fr,fq) needs q[tok=fr][c = wv*32 + fq*8+j], j=0..7
    uint32 w0a = pk2f(aA[0], aA[1]), w1a = pk2f(aA[2], aA[3]);
    uint32 w0b = pk2f(aB[0], aB[1]), w1b = pk2f(aB[2], aB[3]);
    int srcA = fr + 32 * (fq & 1), srcB = srcA + 16;
    uint32 a0A = (uint32)__shfl((int)w0a, srcA), a1A = (uint32)__shfl((int)w1a, srcA);
    uint32 b0A = (uint32)__shfl((int)w0b, srcA), b1A = (uint32)__shfl((int)w1b, srcA);
    uint32 a0B = (uint32)__shfl((int)w0a, srcB), a1B = (uint32)__shfl((int)w1a, srcB);
    uint32 b0B = (uint32)__shfl((int)w0b, srcB), b1B = (uint32)__shfl((int)w1b, srcB);
    bool thi = (fq >> 1) != 0;
    F16x8U bu;
    bu.u4.x = thi ? b0A : a0A;   // j=0,1
    bu.u4.y = thi ? b1A : a1A;   // j=2,3
    bu.u4.z = thi ? b0B : a0B;   // j=4,5
    bu.u4.w = thi ? b1B : a1B;   // j=6,7
    // P2: qw[wv][tok][i] -> QWs[st] rows wv*16+tok
#pragma unroll
    for (int nt = 0; nt < 8; ++nt) {
      f32x4 acc = mfma16(bq[nt], bu.v, ZZ);
      uint2 u; u.x = pk2f(acc[0], acc[1]); u.y = pk2f(acc[2], acc[3]);
      *reinterpret_cast<uint2*>(&QWs[st][(wv * 16 + fr) * LDW + nt * 16 + fq * 4]) = u;
    }
  }
  BAR();  // B: qw ready (all heads)

  // ---- P3: wave-local attention, both streams interleaved ----
  {
    const int kr = lane >> 4, i8 = (lane & 15) * 8;
    const int l2 = 2 * lane;
    const float SCALE = 0.17677669529663687f;  // 1/sqrt(32)
#pragma unroll 1
    for (int lt = 0; lt < 4; ++lt) {
      const int ltok = ltb + lt;
      WAITLGKM();   // prior iter's ds_reads of kvw done (WAR)
#pragma unroll
      for (int st = 0; st < 2; ++st) {
        __half* kvw = Us[st] + wv * 1088;
        uint4 u0, u1;
        u0.x = pk2f(pre[st][0].x, pre[st][0].y); u0.y = pk2f(pre[st][0].z, pre[st][0].w);
        u0.z = pk2f(pre[st][1].x, pre[st][1].y); u0.w = pk2f(pre[st][1].z, pre[st][1].w);
        u1.x = pk2f(pre[st][2].x, pre[st][2].y); u1.y = pk2f(pre[st][2].z, pre[st][2].w);
        u1.z = pk2f(pre[st][3].x, pre[st][3].y); u1.w = pk2f(pre[st][3].z, pre[st][3].w);
        *reinterpret_cast<uint4*>(&kvw[kr * LDW + i8]) = u0;        // rows 0..3
        *reinterpret_cast<uint4*>(&kvw[(4 + kr) * LDW + i8]) = u1;  // rows 4..7
      }
      if (lt < 3) {
#pragma unroll
        for (int st = 0; st < 2; ++st) {
          const float4* kv4 = reinterpret_cast<const float4*>(
              kvin + (size_t)(tb + st * 16 + ltok + 1) * 1024);
          pre[st][0] = kv4[2 * lane];       pre[st][1] = kv4[2 * lane + 1];
          pre[st][2] = kv4[2 * lane + 128]; pre[st][3] = kv4[2 * lane + 129];
        }
      }
      WAITLGKM();   // kv writes visible within wave
      f32x4 acc[2];
#pragma unroll
      for (int st = 0; st < 2; ++st) {
        __half* kvw = Us[st] + wv * 1088;
        f32x4 a = ZZ;
#pragma unroll
        for (int ks = 0; ks < 4; ++ks) {
          f16x8 a_ = ldsv8(&QWs[st][((fr & 3) * 16 + ltok) * LDW + ks * 32 + fq * 8]);
          f16x8 b_ = ldsv8(&kvw[(fr & 7) * LDW + ks * 32 + fq * 8]);
          a = mfma16(a_, b_, a);
        }
        acc[st] = a;
      }
      float at_[2][4];
#pragma unroll
      for (int st = 0; st < 2; ++st) {
#pragma unroll
        for (int r = 0; r < 4; ++r) {
          float s = acc[st][r] * SCALE;
          float mx = fmaxf(s, dppmov<0xB1>(s));
          mx = fmaxf(mx, dppmov<0x4E>(mx));
          mx = fmaxf(mx, swzf<0x101F>(mx));
          float e = __expf(s - mx);
          float dn = e + dppmov<0xB1>(e);
          dn += dppmov<0x4E>(dn);
          dn += swzf<0x101F>(dn);
          at_[st][r] = __fdividef(e, dn);
        }
      }
#pragma unroll
      for (int st = 0; st < 2; ++st) {
        __half* kvw = Us[st] + wv * 1088;
        __half2 kvc[8];
#pragma unroll
        for (int k = 0; k < 8; ++k)
          kvc[k] = *reinterpret_cast<const __half2*>(&kvw[k * LDW + l2]);
#pragma unroll
        for (int h = 0; h < 4; ++h) {
          float c0 = 0.f, c1 = 0.f;
#pragma unroll
          for (int k = 0; k < 8; ++k) {
            float a = bcast(at_[st][h], k);
            float2 kf = __half22float2(kvc[k]);
            c0 = fmaf(a, kf.x, c0);
            c1 = fmaf(a, kf.y, c1);
          }
          *reinterpret_cast<__half2*>(&QWs[st][(h * 16 + ltok) * LDW + l2]) =
              __floats2half2_rn(c0, c1);
        }
      }
    }
  }
  LOADB2(OFF_WV, wv, 4 + wv, bf);
  BAR();  // C: ctx ready; kvw reads done; bf(wv) in flight

  // ---- P4: out = WvT(A) @ ctx(B) -> Ob[tok][c] ----
  {
    const int h1 = wv >> 1, h2 = 2 + (wv >> 1);
#pragma unroll
    for (int st = 0; st < 2; ++st) {
      f32x4 a1c = ZZ, a2c = ZZ;
#pragma unroll
      for (int ks = 0; ks < 4; ++ks) {
        f16x8 b1f = ldsv8(&QWs[st][(h1 * 16 + fr) * LDW + ks * 32 + fq * 8]);
        a1c = mfma16(bf[0][ks], b1f, a1c);
        f16x8 b2f = ldsv8(&QWs[st][(h2 * 16 + fr) * LDW + ks * 32 + fq * 8]);
        a2c = mfma16(bf[1][ks], b2f, a2c);
      }
      stp(Us[st], fr, fq, wv, a1c);
      stp(Us[st], fr, fq, 4 + wv, a2c);
    }
  }
  LOADB2(OFF_WMH, wv, 4 + wv, bf);
  // prefetch this lane's residual x in C-frag layout (token fr, cols cA/cB)
  float4 xqA[2], xqB[2];
#pragma unroll
  for (int st = 0; st < 2; ++st) {
    const float* xrow = xq + (size_t)(tb + st * 16 + fr) * 128;
    xqA[st] = *reinterpret_cast<const float4*>(xrow + cA);
    xqB[st] = *reinterpret_cast<const float4*>(xrow + cB);
  }
  BAR();  // D: Ob ready; bf(wmh)/xq in flight

  // ---- P5 + LN1 stats in C-frag layout (token = fr, all tokens in parallel) ----
  float vv[2][8];
  {
    float4 bmA = *reinterpret_cast<const float4*>(&bmh[cA]);
    float4 bmB = *reinterpret_cast<const float4*>(&bmh[cB]);
#pragma unroll
    for (int st = 0; st < 2; ++st) {
      f32x4 aA = ZZ, aB = ZZ;
      GEMM2(Us[st], bf, aA, aB);
      vv[st][0] = aA[0] + bmA.x; vv[st][1] = aA[1] + bmA.y;
      vv[st][2] = aA[2] + bmA.z; vv[st][3] = aA[3] + bmA.w;
      vv[st][4] = aB[0] + bmB.x; vv[st][5] = aB[1] + bmB.y;
      vv[st][6] = aB[2] + bmB.z; vv[st][7] = aB[3] + bmB.w;
      float s = 0.f, sq = 0.f;
#pragma unroll
      for (int r = 0; r < 8; ++r) { s += vv[st][r]; sq = fmaf(vv[st][r], vv[st][r], sq); }
      s += swzf<0x401F>(s);  s += __shfl_xor(s, 32);    // combine 4 fq-lanes
      sq += swzf<0x401F>(sq); sq += __shfl_xor(sq, 32);
      if (fq == 0) { PART[st][0][fr][wv] = s; PART[st][1][fr][wv] = sq; }
    }
  }
  LOADB2(OFF_W1, wv, 4 + wv, bf);
  BAR();  // E': LN1 partials ready; bf(w1) in flight

  // ---- LN1 finish: combine 4 wave-partials, normalize own cols, + residual -> RESb ----
  {
    float4 gA = *reinterpret_cast<const float4*>(&g1[cA]);
    float4 gB = *reinterpret_cast<const float4*>(&g1[cB]);
    float4 cAv = *reinterpret_cast<const float4*>(&bb1[cA]);
    float4 cBv = *reinterpret_cast<const float4*>(&bb1[cB]);
#pragma unroll
    for (int st = 0; st < 2; ++st) {
      float4 ps = *reinterpret_cast<const float4*>(&PART[st][0][fr][0]);
      float4 pq = *reinterpret_cast<const float4*>(&PART[st][1][fr][0]);
      float su = (ps.x + ps.y) + (ps.z + ps.w);
      float squ = (pq.x + pq.y) + (pq.z + pq.w);
      float mu = su * 0.0078125f;
      float var = squ * 0.0078125f - mu * mu;
      float rstd = rsqrtf(var + 1e-5f);
      float rA0 = (vv[st][0] - mu) * rstd * gA.x + cAv.x + xqA[st].x;
      float rA1 = (vv[st][1] - mu) * rstd * gA.y + cAv.y + xqA[st].y;
      float rA2 = (vv[st][2] - mu) * rstd * gA.z + cAv.z + xqA[st].z;
      float rA3 = (vv[st][3] - mu) * rstd * gA.w + cAv.w + xqA[st].w;
      float rB0 = (vv[st][4] - mu) * rstd * gB.x + cBv.x + xqB[st].x;
      float rB1 = (vv[st][5] - mu) * rstd * gB.y + cBv.y + xqB[st].y;
      float rB2 = (vv[st][6] - mu) * rstd * gB.z + cBv.z + xqB[st].z;
      float rB3 = (vv[st][7] - mu) * rstd * gB.w + cBv.w + xqB[st].w;
      uint2 ua, ub;
      ua.x = pk2f(rA0, rA1); ua.y = pk2f(rA2, rA3);
      ub.x = pk2f(rB0, rB1); ub.y = pk2f(rB2, rB3);
      *reinterpret_cast<uint2*>(&QWs[st][(16 + fr) * LDW + cA]) = ua;  // RESb
      *reinterpret_cast<uint2*>(&QWs[st][(16 + fr) * LDW + cB]) = ub;
    }
  }
  BAR();  // E: RESb ready

  // ---- P6: h = gelu(W1(A) @ res(B) + b1) -> Hb (QWs rows 32-47) ----
  {
    float4 b1a = *reinterpret_cast<const float4*>(&b1[cA]);
    float4 b1b = *reinterpret_cast<const float4*>(&b1[cB]);
#pragma unroll
    for (int st = 0; st < 2; ++st) {
      f32x4 aA = ZZ, aB = ZZ;
      GEMM2(QWs[st] + 16 * LDW, bf, aA, aB);
      uint2 ua, ub;
      float t0, t1;
      t0 = aA[0] + b1a.x; t0 = 0.5f * t0 * (1.f + erff(t0 * 0.70710678118654752f));
      t1 = aA[1] + b1a.y; t1 = 0.5f * t1 * (1.f + erff(t1 * 0.70710678118654752f));
      ua.x = pk2f(t0, t1);
      t0 = aA[2] + b1a.z; t0 = 0.5f * t0 * (1.f + erff(t0 * 0.70710678118654752f));
      t1 = aA[3] + b1a.w; t1 = 0.5f * t1 * (1.f + erff(t1 * 0.70710678118654752f));
      ua.y = pk2f(t0, t1);
      t0 = aB[0] + b1b.x; t0 = 0.5f * t0 * (1.f + erff(t0 * 0.70710678118654752f));
      t1 = aB[1] + b1b.y; t1 = 0.5f * t1 * (1.f + erff(t1 * 0.70710678118654752f));
      ub.x = pk2f(t0, t1);
      t0 = aB[2] + b1b.z; t0 = 0.5f * t0 * (1.f + erff(t0 * 0.70710678118654752f));
      t1 = aB[3] + b1b.w; t1 = 0.5f * t1 * (1.f + erff(t1 * 0.70710678118654752f));
      ub.y = pk2f(t0, t1);
      *reinterpret_cast<uint2*>(&QWs[st][(32 + fr) * LDW + cA]) = ua;
      *reinterpret_cast<uint2*>(&QWs[st][(32 + fr) * LDW + cB]) = ub;
    }
  }
  LOADB2(OFF_W2, wv, 4 + wv, bf);
  BAR();  // F: Hb ready; bf(w2) in flight

  // ---- P7 + LN2 stats in C-frag layout ----
  float ww[2][8];
  {
    float4 b2a = *reinterpret_cast<const float4*>(&b2[cA]);
    float4 b2b = *reinterpret_cast<const float4*>(&b2[cB]);
#pragma unroll
    for (int st = 0; st < 2; ++st) {
      f32x4 aA = ZZ, aB = ZZ;
      GEMM2(QWs[st] + 32 * LDW, bf, aA, aB);
      F16x8U ra, rb;
      ra.u2[0] = *reinterpret_cast<const uint2*>(&QWs[st][(16 + fr) * LDW + cA]);
      rb.u2[0] = *reinterpret_cast<const uint2*>(&QWs[st][(16 + fr) * LDW + cB]);
      float2 p0 = __half22float2(ra.h2[0]), p1 = __half22float2(ra.h2[1]);
      float2 p2 = __half22float2(rb.h2[0]), p3 = __half22float2(rb.h2[1]);
      ww[st][0] = aA[0] + b2a.x + p0.x; ww[st][1] = aA[1] + b2a.y + p0.y;
      ww[st][2] = aA[2] + b2a.z + p1.x; ww[st][3] = aA[3] + b2a.w + p1.y;
      ww[st][4] = aB[0] + b2b.x + p2.x; ww[st][5] = aB[1] + b2b.y + p2.y;
      ww[st][6] = aB[2] + b2b.z + p3.x; ww[st][7] = aB[3] + b2b.w + p3.y;
      float s = 0.f, sq = 0.f;
#pragma unroll
      for (int r = 0; r < 8; ++r) { s += ww[st][r]; sq = fmaf(ww[st][r], ww[st][r], sq); }
      s += swzf<0x401F>(s);  s += __shfl_xor(s, 32);
      sq += swzf<0x401F>(sq); sq += __shfl_xor(sq, 32);
      if (fq == 0) { PART[st][0][fr][wv] = s; PART[st][1][fr][wv] = sq; }
    }
  }
  BAR();  // G: LN2 partials ready

  // ---- LN2 finish + coalesced float4 store straight from C-frag ----
  {
    float4 gA = *reinterpret_cast<const float4*>(&g2[cA]);
    float4 gB = *reinterpret_cast<const float4*>(&g2[cB]);
    float4 cAv = *reinterpret_cast<const float4*>(&bb2[cA]);
    float4 cBv = *reinterpret_cast<const float4*>(&bb2[cB]);
#pragma unroll
    for (int st = 0; st < 2; ++st) {
      float4 ps = *reinterpret_cast<const float4*>(&PART[st][0][fr][0]);
      float4 pq = *reinterpret_cast<const float4*>(&PART[st][1][fr][0]);
      float su = (ps.x + ps.y) + (ps.z + ps.w);
      float squ = (pq.x + pq.y) + (pq.z + pq.w);
      float mu = su * 0.0078125f;
      float var = squ * 0.0078125f - mu * mu;
      float rstd = rsqrtf(var + 1e-5f);
      float4 oA, oB;
      oA.x = (ww[st][0] - mu) * rstd * gA.x + cAv.x;
      oA.y = (ww[st][1] - mu) * rstd * gA.y + cAv.y;
      oA.z = (ww[st][2] - mu) * rstd * gA.z + cAv.z;
      oA.w = (ww[st][3] - mu) * rstd * gA.w + cAv.w;
      oB.x = (ww[st][4] - mu) * rstd * gB.x + cBv.x;
      oB.y = (ww[st][5] - mu) * rstd * gB.y + cBv.y;
      oB.z = (ww[st][6] - mu) * rstd * gB.z + cBv.z;
      oB.w = (ww[st][7] - mu) * rstd * gB.w + cBv.w;
      float* orow = outp + (size_t)(tb + st * 16 + fr) * 128;
      *reinterpret_cast<float4*>(orow + cA) = oA;
      *reinterpret_cast<float4*>(orow + cB) = oB;
    }
  }
}

extern "C" void kernel_launch(void* const* d_in, const int* in_sizes, int n_in,
                              void* d_out, int out_size, void* d_ws, size_t ws_size,
                              hipStream_t stream) {
  const float* xq = (const float*)d_in[0];
  const float* kv = (const float*)d_in[1];
  const float* wkv = (const float*)d_in[2];
  const float* wq = (const float*)d_in[3];
  const float* wmh = (const float*)d_in[4];
  const float* bmh = (const float*)d_in[5];
  const float* w1 = (const float*)d_in[6];
  const float* b1 = (const float*)d_in[7];
  const float* w2 = (const float*)d_in[8];
  const float* b2 = (const float*)d_in[9];
  const float* g1 = (const float*)d_in[10];
  const float* bb1 = (const float*)d_in[11];
  const float* g2 = (const float*)d_in[12];
  const float* bb2 = (const float*)d_in[13];
  __half* ws = (__half*)d_ws;

  prep_weights<<<(WS_HALVES + 255) / 256, 256, 0, stream>>>(wq, wkv, wmh, w1, w2, ws);

  const int tokens = 32768;
  ca_mfma<<<tokens / TB, 256, 0, stream>>>(xq, kv, ws, bmh, b1, b2,
                                           g1, bb1, g2, bb2, (float*)d_out);
}

// Round 15
// 53.588 us; speedup vs baseline: 2.5256x; 1.0613x over previous
//
#include <hip/hip_runtime.h>
#include <hip/hip_fp16.h>

typedef _Float16 f16x8 __attribute__((ext_vector_type(8)));
typedef float f32x4 __attribute__((ext_vector_type(4)));
typedef unsigned int uint32;

#define LDW 136   // row stride in halves (272B: 16B-aligned)
#define TB  32    // tokens per block: two independent 16-token streams

// wait only lgkmcnt(0): vmcnt=63, expcnt=7, lgkmcnt=0 -> 0xC07F
#define WAITLGKM() do { __builtin_amdgcn_s_waitcnt(0xC07F); __builtin_amdgcn_sched_barrier(0); } while(0)

// lgkm-only barrier: leaves global (VGPR-destined) prefetches in flight.
#define BAR() do {                                          \
  asm volatile("s_waitcnt lgkmcnt(0)" ::: "memory");        \
  __builtin_amdgcn_sched_barrier(0);                        \
  __builtin_amdgcn_s_barrier();                             \
  __builtin_amdgcn_sched_barrier(0);                        \
} while (0)

// T5: favor MFMA-burst waves on the CU scheduler (phase-diverse resident blocks)
#define PRIO1() __builtin_amdgcn_s_setprio(1)
#define PRIO0() __builtin_amdgcn_s_setprio(0)

union F16x8U { f16x8 v; __half2 h2[4]; uint2 u2[2]; uint4 u4; };

__device__ __forceinline__ uint32 pk2f(float a, float b) {
  __half2 h = __floats2half2_rn(a, b);
  return *reinterpret_cast<uint32*>(&h);
}
__device__ __forceinline__ float bcast(float v, int sl) {
  return __int_as_float(__builtin_amdgcn_readlane(__float_as_int(v), sl));
}
template <int CTRL, int RMASK = 0xF, int BMASK = 0xF>
__device__ __forceinline__ float dppmov(float v) {
  return __int_as_float(__builtin_amdgcn_update_dpp(
      0, __float_as_int(v), CTRL, RMASK, BMASK, true));
}
template <int PAT>
__device__ __forceinline__ float swzf(float v) {
  return __int_as_float(__builtin_amdgcn_ds_swizzle(__float_as_int(v), PAT));
}
__device__ __forceinline__ f16x8 ldsv8(const __half* p) {
  return *reinterpret_cast<const f16x8*>(p);   // ds_read_b128
}
__device__ __forceinline__ f32x4 mfma16(f16x8 a, f16x8 b, f32x4 c) {
  return __builtin_amdgcn_mfma_f32_16x16x32_f16(a, b, c, 0, 0, 0);
}
// packed C-frag store: C[m][n=fr] -> row-major act[tok=fr][c], 1x ds_write_b64
__device__ __forceinline__ void stp(__half* base, int fr, int fq, int nt, f32x4 a) {
  uint2 u; u.x = pk2f(a[0], a[1]); u.y = pk2f(a[2], a[3]);
  *reinterpret_cast<uint2*>(&base[fr * LDW + nt * 16 + fq * 4]) = u;
}

// ---- workspace layout (halves) ----
#define OFF_WQ   0          // wqT  [c_out 128][c_in 128]
#define OFF_WK2  16384      // wk2  [h 4][i 128][d 40] : wkv[i][h*32+d] (d<32, pad 0)
#define OFF_WV   36864      // wvT  [c_out 128][i 128] : wkv[i][128+c]
#define OFF_WMH  53248      // wmhT
#define OFF_W1   69632      // w1T
#define OFF_W2   86016      // w2T
#define WS_HALVES 102400

__global__ void prep_weights(const float* __restrict__ wq, const float* __restrict__ wkv,
                             const float* __restrict__ wmh, const float* __restrict__ w1,
                             const float* __restrict__ w2, __half* __restrict__ ws) {
  int idx = blockIdx.x * 256 + threadIdx.x;
  if (idx >= WS_HALVES) return;
  float v;
  if (idx < OFF_WK2) {
    int t = idx, c = t >> 7, k = t & 127;
    v = wq[k * 128 + c];
  } else if (idx < OFF_WV) {
    int t = idx - OFF_WK2;
    int d = t % 40, row = t / 40;            // row = h*128 + i
    int h = row >> 7, i = row & 127;
    v = (d < 32) ? wkv[i * 256 + h * 32 + d] : 0.f;
  } else if (idx < OFF_WMH) {
    int t = idx - OFF_WV, c = t >> 7, k = t & 127;
    v = wkv[k * 256 + 128 + c];
  } else if (idx < OFF_W1) {
    int t = idx - OFF_WMH, c = t >> 7, k = t & 127;
    v = wmh[k * 128 + c];
  } else if (idx < OFF_W2) {
    int t = idx - OFF_W1, c = t >> 7, k = t & 127;
    v = w1[k * 128 + c];
  } else {
    int t = idx - OFF_W2, c = t >> 7, k = t & 127;
    v = w2[k * 128 + c];
  }
  ws[idx] = __float2half_rn(v);
}

// load W frags (2 c_out-tiles x 4 k-slices), used as MFMA *A* operand (shared by streams)
#define LOADB2(GOFF, NT0, NT1, BF) do {                                          \
  _Pragma("unroll")                                                              \
  for (int t_ = 0; t_ < 2; ++t_) {                                               \
    int nt_ = t_ ? (NT1) : (NT0);                                                \
    _Pragma("unroll")                                                            \
    for (int ks_ = 0; ks_ < 4; ++ks_)                                            \
      BF[t_][ks_] = *reinterpret_cast<const f16x8*>(                             \
          wsv + (GOFF) + (nt_*16 + fr)*128 + ks_*32 + fq*8);                     \
  } } while (0)

// two 16x16 tiles: A = weights (BF), B = activation tile (row-major [tok][c])
#define GEMM2(AT, BF, ACC0, ACC1) do {                                           \
  _Pragma("unroll")                                                              \
  for (int ks_ = 0; ks_ < 4; ++ks_) {                                            \
    f16x8 b_ = ldsv8(&(AT)[fr * LDW + ks_ * 32 + fq * 8]);                       \
    ACC0 = mfma16(BF[0][ks_], b_, ACC0);                                         \
    ACC1 = mfma16(BF[1][ks_], b_, ACC1);                                         \
  } } while (0)

__global__ void __launch_bounds__(256, 3) ca_mfma(
    const float* __restrict__ xq, const float* __restrict__ kvin,
    const __half* __restrict__ wsv,
    const float* __restrict__ bmh, const float* __restrict__ b1,
    const float* __restrict__ b2,
    const float* __restrict__ g1, const float* __restrict__ bb1,
    const float* __restrict__ g2, const float* __restrict__ bb2,
    float* __restrict__ outp)
{
  // LDS: 34816 + 17408 + 1024 = 53248 B -> 3 blocks/CU
  __shared__ __half QWC[2 * 64 * LDW];   // per stream: qw/ctx rows 0-63; RESb 16-31, Hb 32-47 reuse
  __shared__ __half UBUF[2 * 32 * LDW];  // per stream: Xh(0-15)/Qb(16-31) -> kvw -> Ob(0-15)
  __shared__ float  PART[2][2][16][4];   // [stream][s|sq][tok][wave] LN partials

  const int tid = threadIdx.x;
  const int wv = tid >> 6, lane = tid & 63;
  const int fr = lane & 15, fq = lane >> 4;   // MFMA frag row / k-group
  const int tb = blockIdx.x * TB;
  const int ltb = wv * 4;
  const int cA = wv * 16 + fq * 4, cB = 64 + cA;   // this lane's C-frag columns

  __half* const QWs[2] = {QWC, QWC + 64 * LDW};
  __half* const Us[2]  = {UBUF, UBUF + 32 * LDW};

  const f32x4 ZZ = {0.f, 0.f, 0.f, 0.f};

  // ---- entry: prefetch token-0 kv for both streams + P1 W frags (wave-local tiles) ----
  float4 pre[2][4];
#pragma unroll
  for (int st = 0; st < 2; ++st) {
    const float4* kv4 = reinterpret_cast<const float4*>(
        kvin + (size_t)(tb + st * 16 + ltb) * 1024);
    pre[st][0] = kv4[2 * lane];       pre[st][1] = kv4[2 * lane + 1];
    pre[st][2] = kv4[2 * lane + 128]; pre[st][3] = kv4[2 * lane + 129];
  }
  f16x8 bf[2][4];
  LOADB2(OFF_WQ, 2 * wv, 2 * wv + 1, bf);   // wave computes the Q-cols its own P2 needs

  // ---- Xh stage, both streams ----
  {
    int tok = tid >> 4, ko = (tid & 15) * 8;
#pragma unroll
    for (int st = 0; st < 2; ++st) {
      const float4* s0 = reinterpret_cast<const float4*>(
          xq + (size_t)(tb + st * 16 + tok) * 128 + ko);
      float4 a = s0[0], b = s0[1];
      uint4 u; u.x = pk2f(a.x, a.y); u.y = pk2f(a.z, a.w);
      u.z = pk2f(b.x, b.y); u.w = pk2f(b.z, b.w);
      *reinterpret_cast<uint4*>(&Us[st][tok * LDW + ko]) = u;
    }
  }
  BAR();  // A: Xh ready; bf(wq)/kv pre stay in flight

  // ---- P1: Q cols [32wv,32wv+32) for all 16 tokens, both streams ----
  PRIO1();
#pragma unroll
  for (int st = 0; st < 2; ++st) {
    f32x4 aA = ZZ, aB = ZZ;
    GEMM2(Us[st], bf, aA, aB);
    stp(Us[st] + 16 * LDW, fr, fq, 2 * wv, aA);
    stp(Us[st] + 16 * LDW, fr, fq, 2 * wv + 1, aB);
  }
  PRIO0();
  // P2's A = wk2 rows (i), K=32 (shared)
  f16x8 bq[8];
#pragma unroll
  for (int nt = 0; nt < 8; ++nt)
    bq[nt] = *reinterpret_cast<const f16x8*>(
        wsv + OFF_WK2 + (wv * 128 + nt * 16 + fr) * 40 + fq * 8);
  WAITLGKM();  // P1->P2 is wave-local (cols match): no block barrier needed

  // ---- P2: qw[wv][tok][i] -> QWs[st][(wv*16+tok)][i] ----
  PRIO1();
#pragma unroll
  for (int st = 0; st < 2; ++st) {
    f16x8 aq = ldsv8(&Us[st][16 * LDW + fr * LDW + wv * 32 + fq * 8]);
#pragma unroll
    for (int nt = 0; nt < 8; ++nt) {
      f32x4 acc = mfma16(bq[nt], aq, ZZ);
      uint2 u; u.x = pk2f(acc[0], acc[1]); u.y = pk2f(acc[2], acc[3]);
      *reinterpret_cast<uint2*>(&QWs[st][(wv * 16 + fr) * LDW + nt * 16 + fq * 4]) = u;
    }
  }
  PRIO0();
  BAR();  // B: qw ready; Xh/Qb reads done (kvw may overwrite)

  // ---- P3: wave-local attention, both streams interleaved ----
  {
    const int kr = lane >> 4, i8 = (lane & 15) * 8;
    const int l2 = 2 * lane;
    const float SCALE = 0.17677669529663687f;  // 1/sqrt(32)
#pragma unroll 1
    for (int lt = 0; lt < 4; ++lt) {
      const int ltok = ltb + lt;
      WAITLGKM();   // prior iter's ds_reads of kvw done (WAR)
#pragma unroll
      for (int st = 0; st < 2; ++st) {
        __half* kvw = Us[st] + wv * 1088;
        uint4 u0, u1;
        u0.x = pk2f(pre[st][0].x, pre[st][0].y); u0.y = pk2f(pre[st][0].z, pre[st][0].w);
        u0.z = pk2f(pre[st][1].x, pre[st][1].y); u0.w = pk2f(pre[st][1].z, pre[st][1].w);
        u1.x = pk2f(pre[st][2].x, pre[st][2].y); u1.y = pk2f(pre[st][2].z, pre[st][2].w);
        u1.z = pk2f(pre[st][3].x, pre[st][3].y); u1.w = pk2f(pre[st][3].z, pre[st][3].w);
        *reinterpret_cast<uint4*>(&kvw[kr * LDW + i8]) = u0;        // rows 0..3
        *reinterpret_cast<uint4*>(&kvw[(4 + kr) * LDW + i8]) = u1;  // rows 4..7
      }
      if (lt < 3) {
#pragma unroll
        for (int st = 0; st < 2; ++st) {
          const float4* kv4 = reinterpret_cast<const float4*>(
              kvin + (size_t)(tb + st * 16 + ltok + 1) * 1024);
          pre[st][0] = kv4[2 * lane];       pre[st][1] = kv4[2 * lane + 1];
          pre[st][2] = kv4[2 * lane + 128]; pre[st][3] = kv4[2 * lane + 129];
        }
      }
      WAITLGKM();   // kv writes visible within wave
      f32x4 acc[2];
      PRIO1();
#pragma unroll
      for (int st = 0; st < 2; ++st) {
        __half* kvw = Us[st] + wv * 1088;
        f32x4 a = ZZ;
#pragma unroll
        for (int ks = 0; ks < 4; ++ks) {
          f16x8 a_ = ldsv8(&QWs[st][((fr & 3) * 16 + ltok) * LDW + ks * 32 + fq * 8]);
          f16x8 b_ = ldsv8(&kvw[(fr & 7) * LDW + ks * 32 + fq * 8]);
          a = mfma16(a_, b_, a);
        }
        acc[st] = a;
      }
      PRIO0();
      float at_[2][4];
#pragma unroll
      for (int st = 0; st < 2; ++st) {
#pragma unroll
        for (int r = 0; r < 4; ++r) {
          float s = acc[st][r] * SCALE;
          float mx = fmaxf(s, dppmov<0xB1>(s));
          mx = fmaxf(mx, dppmov<0x4E>(mx));
          mx = fmaxf(mx, swzf<0x101F>(mx));
          float e = __expf(s - mx);
          float dn = e + dppmov<0xB1>(e);
          dn += dppmov<0x4E>(dn);
          dn += swzf<0x101F>(dn);
          at_[st][r] = __fdividef(e, dn);
        }
      }
#pragma unroll
      for (int st = 0; st < 2; ++st) {
        __half* kvw = Us[st] + wv * 1088;
        __half2 kvc[8];
#pragma unroll
        for (int k = 0; k < 8; ++k)
          kvc[k] = *reinterpret_cast<const __half2*>(&kvw[k * LDW + l2]);
#pragma unroll
        for (int h = 0; h < 4; ++h) {
          float c0 = 0.f, c1 = 0.f;
#pragma unroll
          for (int k = 0; k < 8; ++k) {
            float a = bcast(at_[st][h], k);
            float2 kf = __half22float2(kvc[k]);
            c0 = fmaf(a, kf.x, c0);
            c1 = fmaf(a, kf.y, c1);
          }
          *reinterpret_cast<__half2*>(&QWs[st][(h * 16 + ltok) * LDW + l2]) =
              __floats2half2_rn(c0, c1);
        }
      }
    }
  }
  LOADB2(OFF_WV, wv, 4 + wv, bf);
  BAR();  // C: ctx ready; kvw reads done; bf(wv) in flight

  // ---- P4: out = WvT(A) @ ctx(B) -> Ob[tok][c] ----
  {
    const int h1 = wv >> 1, h2 = 2 + (wv >> 1);
    PRIO1();
#pragma unroll
    for (int st = 0; st < 2; ++st) {
      f32x4 a1c = ZZ, a2c = ZZ;
#pragma unroll
      for (int ks = 0; ks < 4; ++ks) {
        f16x8 b1f = ldsv8(&QWs[st][(h1 * 16 + fr) * LDW + ks * 32 + fq * 8]);
        a1c = mfma16(bf[0][ks], b1f, a1c);
        f16x8 b2f = ldsv8(&QWs[st][(h2 * 16 + fr) * LDW + ks * 32 + fq * 8]);
        a2c = mfma16(bf[1][ks], b2f, a2c);
      }
      stp(Us[st], fr, fq, wv, a1c);
      stp(Us[st], fr, fq, 4 + wv, a2c);
    }
    PRIO0();
  }
  LOADB2(OFF_WMH, wv, 4 + wv, bf);
  // prefetch this lane's residual x in C-frag layout (token fr, cols cA/cB)
  float4 xqA[2], xqB[2];
#pragma unroll
  for (int st = 0; st < 2; ++st) {
    const float* xrow = xq + (size_t)(tb + st * 16 + fr) * 128;
    xqA[st] = *reinterpret_cast<const float4*>(xrow + cA);
    xqB[st] = *reinterpret_cast<const float4*>(xrow + cB);
  }
  BAR();  // D: Ob ready; bf(wmh)/xq in flight

  // ---- P5 + LN1 stats in C-frag layout (token = fr, all tokens in parallel) ----
  float vv[2][8];
  {
    float4 bmA = *reinterpret_cast<const float4*>(&bmh[cA]);
    float4 bmB = *reinterpret_cast<const float4*>(&bmh[cB]);
#pragma unroll
    for (int st = 0; st < 2; ++st) {
      f32x4 aA = ZZ, aB = ZZ;
      PRIO1();
      GEMM2(Us[st], bf, aA, aB);
      PRIO0();
      vv[st][0] = aA[0] + bmA.x; vv[st][1] = aA[1] + bmA.y;
      vv[st][2] = aA[2] + bmA.z; vv[st][3] = aA[3] + bmA.w;
      vv[st][4] = aB[0] + bmB.x; vv[st][5] = aB[1] + bmB.y;
      vv[st][6] = aB[2] + bmB.z; vv[st][7] = aB[3] + bmB.w;
      float s = 0.f, sq = 0.f;
#pragma unroll
      for (int r = 0; r < 8; ++r) { s += vv[st][r]; sq = fmaf(vv[st][r], vv[st][r], sq); }
      s += swzf<0x401F>(s);  s += __shfl_xor(s, 32);    // combine 4 fq-lanes
      sq += swzf<0x401F>(sq); sq += __shfl_xor(sq, 32);
      if (fq == 0) { PART[st][0][fr][wv] = s; PART[st][1][fr][wv] = sq; }
    }
  }
  LOADB2(OFF_W1, wv, 4 + wv, bf);
  BAR();  // E': LN1 partials ready; bf(w1) in flight

  // ---- LN1 finish: combine 4 wave-partials, normalize own cols, + residual -> RESb ----
  {
    float4 gA = *reinterpret_cast<const float4*>(&g1[cA]);
    float4 gB = *reinterpret_cast<const float4*>(&g1[cB]);
    float4 cAv = *reinterpret_cast<const float4*>(&bb1[cA]);
    float4 cBv = *reinterpret_cast<const float4*>(&bb1[cB]);
#pragma unroll
    for (int st = 0; st < 2; ++st) {
      float4 ps = *reinterpret_cast<const float4*>(&PART[st][0][fr][0]);
      float4 pq = *reinterpret_cast<const float4*>(&PART[st][1][fr][0]);
      float su = (ps.x + ps.y) + (ps.z + ps.w);
      float squ = (pq.x + pq.y) + (pq.z + pq.w);
      float mu = su * 0.0078125f;
      float var = squ * 0.0078125f - mu * mu;
      float rstd = rsqrtf(var + 1e-5f);
      float rA0 = (vv[st][0] - mu) * rstd * gA.x + cAv.x + xqA[st].x;
      float rA1 = (vv[st][1] - mu) * rstd * gA.y + cAv.y + xqA[st].y;
      float rA2 = (vv[st][2] - mu) * rstd * gA.z + cAv.z + xqA[st].z;
      float rA3 = (vv[st][3] - mu) * rstd * gA.w + cAv.w + xqA[st].w;
      float rB0 = (vv[st][4] - mu) * rstd * gB.x + cBv.x + xqB[st].x;
      float rB1 = (vv[st][5] - mu) * rstd * gB.y + cBv.y + xqB[st].y;
      float rB2 = (vv[st][6] - mu) * rstd * gB.z + cBv.z + xqB[st].z;
      float rB3 = (vv[st][7] - mu) * rstd * gB.w + cBv.w + xqB[st].w;
      uint2 ua, ub;
      ua.x = pk2f(rA0, rA1); ua.y = pk2f(rA2, rA3);
      ub.x = pk2f(rB0, rB1); ub.y = pk2f(rB2, rB3);
      *reinterpret_cast<uint2*>(&QWs[st][(16 + fr) * LDW + cA]) = ua;  // RESb
      *reinterpret_cast<uint2*>(&QWs[st][(16 + fr) * LDW + cB]) = ub;
    }
  }
  BAR();  // E: RESb ready

  // ---- P6: h = gelu(W1(A) @ res(B) + b1) -> Hb (QWs rows 32-47) ----
  {
    float4 b1a = *reinterpret_cast<const float4*>(&b1[cA]);
    float4 b1b = *reinterpret_cast<const float4*>(&b1[cB]);
#pragma unroll
    for (int st = 0; st < 2; ++st) {
      f32x4 aA = ZZ, aB = ZZ;
      PRIO1();
      GEMM2(QWs[st] + 16 * LDW, bf, aA, aB);
      PRIO0();
      uint2 ua, ub;
      float t0, t1;
      t0 = aA[0] + b1a.x; t0 = 0.5f * t0 * (1.f + erff(t0 * 0.70710678118654752f));
      t1 = aA[1] + b1a.y; t1 = 0.5f * t1 * (1.f + erff(t1 * 0.70710678118654752f));
      ua.x = pk2f(t0, t1);
      t0 = aA[2] + b1a.z; t0 = 0.5f * t0 * (1.f + erff(t0 * 0.70710678118654752f));
      t1 = aA[3] + b1a.w; t1 = 0.5f * t1 * (1.f + erff(t1 * 0.70710678118654752f));
      ua.y = pk2f(t0, t1);
      t0 = aB[0] + b1b.x; t0 = 0.5f * t0 * (1.f + erff(t0 * 0.70710678118654752f));
      t1 = aB[1] + b1b.y; t1 = 0.5f * t1 * (1.f + erff(t1 * 0.70710678118654752f));
      ub.x = pk2f(t0, t1);
      t0 = aB[2] + b1b.z; t0 = 0.5f * t0 * (1.f + erff(t0 * 0.70710678118654752f));
      t1 = aB[3] + b1b.w; t1 = 0.5f * t1 * (1.f + erff(t1 * 0.70710678118654752f));
      ub.y = pk2f(t0, t1);
      *reinterpret_cast<uint2*>(&QWs[st][(32 + fr) * LDW + cA]) = ua;
      *reinterpret_cast<uint2*>(&QWs[st][(32 + fr) * LDW + cB]) = ub;
    }
  }
  LOADB2(OFF_W2, wv, 4 + wv, bf);
  BAR();  // F: Hb ready; bf(w2) in flight

  // ---- P7 + LN2 stats in C-frag layout ----
  float ww[2][8];
  {
    float4 b2a = *reinterpret_cast<const float4*>(&b2[cA]);
    float4 b2b = *reinterpret_cast<const float4*>(&b2[cB]);
#pragma unroll
    for (int st = 0; st < 2; ++st) {
      f32x4 aA = ZZ, aB = ZZ;
      PRIO1();
      GEMM2(QWs[st] + 32 * LDW, bf, aA, aB);
      PRIO0();
      F16x8U ra, rb;
      ra.u2[0] = *reinterpret_cast<const uint2*>(&QWs[st][(16 + fr) * LDW + cA]);
      rb.u2[0] = *reinterpret_cast<const uint2*>(&QWs[st][(16 + fr) * LDW + cB]);
      float2 p0 = __half22float2(ra.h2[0]), p1 = __half22float2(ra.h2[1]);
      float2 p2 = __half22float2(rb.h2[0]), p3 = __half22float2(rb.h2[1]);
      ww[st][0] = aA[0] + b2a.x + p0.x; ww[st][1] = aA[1] + b2a.y + p0.y;
      ww[st][2] = aA[2] + b2a.z + p1.x; ww[st][3] = aA[3] + b2a.w + p1.y;
      ww[st][4] = aB[0] + b2b.x + p2.x; ww[st][5] = aB[1] + b2b.y + p2.y;
      ww[st][6] = aB[2] + b2b.z + p3.x; ww[st][7] = aB[3] + b2b.w + p3.y;
      float s = 0.f, sq = 0.f;
#pragma unroll
      for (int r = 0; r < 8; ++r) { s += ww[st][r]; sq = fmaf(ww[st][r], ww[st][r], sq); }
      s += swzf<0x401F>(s);  s += __shfl_xor(s, 32);
      sq += swzf<0x401F>(sq); sq += __shfl_xor(sq, 32);
      if (fq == 0) { PART[st][0][fr][wv] = s; PART[st][1][fr][wv] = sq; }
    }
  }
  BAR();  // G: LN2 partials ready

  // ---- LN2 finish + coalesced float4 store straight from C-frag ----
  {
    float4 gA = *reinterpret_cast<const float4*>(&g2[cA]);
    float4 gB = *reinterpret_cast<const float4*>(&g2[cB]);
    float4 cAv = *reinterpret_cast<const float4*>(&bb2[cA]);
    float4 cBv = *reinterpret_cast<const float4*>(&bb2[cB]);
#pragma unroll
    for (int st = 0; st < 2; ++st) {
      float4 ps = *reinterpret_cast<const float4*>(&PART[st][0][fr][0]);
      float4 pq = *reinterpret_cast<const float4*>(&PART[st][1][fr][0]);
      float su = (ps.x + ps.y) + (ps.z + ps.w);
      float squ = (pq.x + pq.y) + (pq.z + pq.w);
      float mu = su * 0.0078125f;
      float var = squ * 0.0078125f - mu * mu;
      float rstd = rsqrtf(var + 1e-5f);
      float4 oA, oB;
      oA.x = (ww[st][0] - mu) * rstd * gA.x + cAv.x;
      oA.y = (ww[st][1] - mu) * rstd * gA.y + cAv.y;
      oA.z = (ww[st][2] - mu) * rstd * gA.z + cAv.z;
      oA.w = (ww[st][3] - mu) * rstd * gA.w + cAv.w;
      oB.x = (ww[st][4] - mu) * rstd * gB.x + cBv.x;
      oB.y = (ww[st][5] - mu) * rstd * gB.y + cBv.y;
      oB.z = (ww[st][6] - mu) * rstd * gB.z + cBv.z;
      oB.w = (ww[st][7] - mu) * rstd * gB.w + cBv.w;
      float* orow = outp + (size_t)(tb + st * 16 + fr) * 128;
      *reinterpret_cast<float4*>(orow + cA) = oA;
      *reinterpret_cast<float4*>(orow + cB) = oB;
    }
  }
}

extern "C" void kernel_launch(void* const* d_in, const int* in_sizes, int n_in,
                              void* d_out, int out_size, void* d_ws, size_t ws_size,
                              hipStream_t stream) {
  const float* xq = (const float*)d_in[0];
  const float* kv = (const float*)d_in[1];
  const float* wkv = (const float*)d_in[2];
  const float* wq = (const float*)d_in[3];
  const float* wmh = (const float*)d_in[4];
  const float* bmh = (const float*)d_in[5];
  const float* w1 = (const float*)d_in[6];
  const float* b1 = (const float*)d_in[7];
  const float* w2 = (const float*)d_in[8];
  const float* b2 = (const float*)d_in[9];
  const float* g1 = (const float*)d_in[10];
  const float* bb1 = (const float*)d_in[11];
  const float* g2 = (const float*)d_in[12];
  const float* bb2 = (const float*)d_in[13];
  __half* ws = (__half*)d_ws;

  prep_weights<<<(WS_HALVES + 255) / 256, 256, 0, stream>>>(wq, wkv, wmh, w1, w2, ws);

  const int tokens = 32768;
  ca_mfma<<<tokens / TB, 256, 0, stream>>>(xq, kv, ws, bmh, b1, b2,
                                           g1, bb1, g2, bb2, (float*)d_out);
}